// Round 4
// baseline (173.162 us; speedup 1.0000x reference)
//
#include <hip/hip_runtime.h>

typedef unsigned short u16;
typedef unsigned int u32;
typedef __bf16 bf16x8 __attribute__((ext_vector_type(8)));
typedef float f32x16 __attribute__((ext_vector_type(16)));

#define C2 (-7.213475204444817f) /* -5/ln2 : exp(-5 t^2) = exp2(C2 t^2) */
#define T1C 0.28650480f          /* e^-1.25 */
#define T2C 0.0067379470f        /* e^-5    */

__device__ __forceinline__ u16 f2bf(float f) {
  u32 u = __float_as_uint(f);
  return (u16)((u + 0x7FFFu + ((u >> 16) & 1u)) >> 16);  // RNE
}

__device__ __forceinline__ void async16(const void* g, void* l) {
  __builtin_amdgcn_global_load_lds(
      (const __attribute__((address_space(1))) u32*)g,
      (__attribute__((address_space(3))) u32*)l, 16, 0, 0);
}

__device__ __forceinline__ f32x16 mfma16(uint4 a, uint4 b, f32x16 c) {
  return __builtin_amdgcn_mfma_f32_32x32x16_bf16(
      __builtin_bit_cast(bf16x8, a), __builtin_bit_cast(bf16x8, b), c, 0, 0, 0);
}

// ---------------------------------------------------------------------------
// Prep (unchanged from R3, works): f32 weights -> bf16 transposed.
// wst[s][u][d]: s=0..4 -> spline_weight[d][u][s]; s=5 -> base_weight[d][u].
// ---------------------------------------------------------------------------
__global__ __launch_bounds__(256) void kan_prep(const float* __restrict__ wb,
                                                const float* __restrict__ ws,
                                                u16* __restrict__ wst) {
  __shared__ __align__(16) u16 tile[6][32][40];
  const int t = threadIdx.x;
  const int d0 = blockIdx.x * 32;
  const int u0 = blockIdx.y * 32;
#pragma unroll
  for (int it = 0; it < 4; ++it) {
    int e = it * 256 + t;
    int uu = e & 31, dd = e >> 5;
    const float* p = ws + ((size_t)(d0 + dd) * 128 + (u0 + uu)) * 8;
    float4 v0 = *(const float4*)p;
    float g4 = p[4];
    tile[0][uu][dd] = f2bf(v0.x);
    tile[1][uu][dd] = f2bf(v0.y);
    tile[2][uu][dd] = f2bf(v0.z);
    tile[3][uu][dd] = f2bf(v0.w);
    tile[4][uu][dd] = f2bf(g4);
    tile[5][uu][dd] = f2bf(wb[(size_t)(d0 + dd) * 128 + (u0 + uu)]);
  }
  __syncthreads();
#pragma unroll
  for (int it = 0; it < 3; ++it) {
    int v = it * 256 + t;
    int s = v >> 7;
    int r = v & 127;
    int uu = r >> 2, dseg = r & 3;
    uint4 val = *(const uint4*)&tile[s][uu][dseg * 8];
    *(uint4*)(wst + (size_t)(s * 128 + u0 + uu) * 1024 + d0 + dseg * 8) = val;
  }
}

// ---------------------------------------------------------------------------
// Main. grid 512 = 256 m-tiles x 2 n-halves (pair-swizzled to share XCD).
// Block: 256 thr / 4 waves (2m x 2n), tile M=64 N=64, wave 32x32.
// A-fragments (5 rbf subs + bf16(x)) computed IN REGISTERS per lane from a
// direct f32 x load: lane (ml,kh) of wave wm owns row wm*32+ml and supplies
// A[m][k = kk*16 + kh*8 + j]  (layout validated in R2/R3).
// Bs: frag-order LDS (lane i reads base + i*16 -> conflict-free; DMA dest is
// the same linear order): byte = buf*24576 + s*4096 + kk*2048 + wn*1024 + l*16
// Double-buffered 2x24 KB = 48 KB -> 2 blocks/CU for cross-block stall cover.
// C/D: col=lane&31 (n), row=(reg&3)+8*(reg>>2)+4*(lane>>5) (m).
// ---------------------------------------------------------------------------
__global__ __launch_bounds__(256, 2) void kan_main(const float* __restrict__ x,
                                                   const u16* __restrict__ wst,
                                                   float* __restrict__ out) {
  __shared__ __align__(16) u16 Bs[2][6][2][2][64][8];  // 49152 B
  char* bsf = (char*)&Bs[0][0][0][0][0][0];

  const int t = threadIdx.x;
  const int lane = t & 63;
  const int w = t >> 6;
  const int wm = w >> 1, wn = w & 1;
  const int ml = lane & 31, kh = lane >> 5;

  const int bx = blockIdx.x;
  const int mt = (bx & 7) | ((bx >> 4) << 3);  // m-tile 0..255
  const int nh = (bx >> 3) & 1;                // n-half: twin at bx^8 (same XCD)
  const int b0 = mt * 64;
  const int u0 = nh * 64;

  f32x16 accb, accs;
#pragma unroll
  for (int i = 0; i < 16; ++i) { accb[i] = 0.f; accs[i] = 0.f; }

  // DMA roles: thread t -> s-loop; granule (kk=t>>7, wn=(t>>6)&1, l=t&63)
  //   src = wst[s][u0 + wn*32 + (l&31)][k0 + kk*16 + (l>>5)*8]
  //   dst = buf + s*4096 + t*16   (lane-linear within wave)
  const u16* dsrc = wst + (size_t)(u0 + ((t >> 6) & 1) * 32 + (t & 31)) * 1024 +
                    ((t >> 7) << 4) + (((t >> 5) & 1) << 3);

  // x: lane reads its own row, cols k0 + kh*8 + {0..8} (kk=0), +16 (kk=1)
  const float* xp = x + (size_t)(b0 + wm * 32 + ml) * 1024 + kh * 8;

  auto dma = [&](int k0, int buf) {
    const u16* s0 = dsrc + k0;
    char* d0 = bsf + buf * 24576 + t * 16;
#pragma unroll
    for (int s = 0; s < 6; ++s) async16(s0 + (size_t)s * 131072, d0 + s * 4096);
  };

  // 8 x-values -> 6 A-fragments (5 rbf + x), bf16 via +0x8000 round + v_perm
  auto mkfrags = [&](float4 a, float4 b, uint4* fr) {
    float xf[8] = {a.x, a.y, a.z, a.w, b.x, b.y, b.z, b.w};
    u32 rb[6][8];
#pragma unroll
    for (int e = 0; e < 8; ++e) {
      float xv = xf[e];
      float t0 = C2 * xv;
      float P = __builtin_amdgcn_exp2f(t0 * xv);  // e^{-5x^2}
      float Qp = __builtin_amdgcn_exp2f(-t0);     // e^{+5x}
      float Qm = __builtin_amdgcn_exp2f(t0);      // e^{-5x}
      float PQ = P * Qp, PQm = P * Qm;
      rb[0][e] = __float_as_uint(PQm * Qm * T2C) + 0x8000u;
      rb[1][e] = __float_as_uint(PQm * T1C) + 0x8000u;
      rb[2][e] = __float_as_uint(P) + 0x8000u;
      rb[3][e] = __float_as_uint(PQ * T1C) + 0x8000u;
      rb[4][e] = __float_as_uint(PQ * Qp * T2C) + 0x8000u;
      rb[5][e] = __float_as_uint(xv) + 0x8000u;
    }
#pragma unroll
    for (int s = 0; s < 6; ++s) {
      fr[s].x = __builtin_amdgcn_perm(rb[s][1], rb[s][0], 0x07060302);
      fr[s].y = __builtin_amdgcn_perm(rb[s][3], rb[s][2], 0x07060302);
      fr[s].z = __builtin_amdgcn_perm(rb[s][5], rb[s][4], 0x07060302);
      fr[s].w = __builtin_amdgcn_perm(rb[s][7], rb[s][6], 0x07060302);
    }
  };

  // ---- prologue
  float4 xc0 = *(const float4*)(xp + 0);
  float4 xc1 = *(const float4*)(xp + 4);
  float4 xc2 = *(const float4*)(xp + 16);
  float4 xc3 = *(const float4*)(xp + 20);
  dma(0, 0);
  __syncthreads();

  u32 bufoff = 0;
  for (int k = 0; k < 32; ++k) {
    float4 xn0, xn1, xn2, xn3;
    if (k < 31) {
      dma((k + 1) * 32, (k + 1) & 1);  // in flight under the VALU below
      const float* xq = xp + (k + 1) * 32;
      xn0 = *(const float4*)(xq + 0);
      xn1 = *(const float4*)(xq + 4);
      xn2 = *(const float4*)(xq + 16);
      xn3 = *(const float4*)(xq + 20);
    }

    uint4 fr0[6], fr1[6];
    mkfrags(xc0, xc1, fr0);  // kk = 0
    mkfrags(xc2, xc3, fr1);  // kk = 1

    const char* bb = bsf + bufoff + wn * 1024 + lane * 16;
#pragma unroll
    for (int s = 0; s < 6; ++s) {
      uint4 b0v = *(const uint4*)(bb + s * 4096);         // kk=0
      uint4 b1v = *(const uint4*)(bb + s * 4096 + 2048);  // kk=1
      if (s < 5) {
        accs = mfma16(fr0[s], b0v, accs);
        accs = mfma16(fr1[s], b1v, accs);
      } else {
        accb = mfma16(fr0[s], b0v, accb);
        accb = mfma16(fr1[s], b1v, accb);
      }
    }
    __syncthreads();  // drains next-chunk DMA; protects buf reuse
    bufoff ^= 24576;
    xc0 = xn0; xc1 = xn1; xc2 = xn2; xc3 = xn3;
  }

  // ---- epilogue: silu(base) + spline, f32 stores
  const int nq = u0 + wn * 32 + ml;
#pragma unroll
  for (int reg = 0; reg < 16; ++reg) {
    int row = (reg & 3) + 8 * (reg >> 2) + 4 * kh;
    int m = b0 + wm * 32 + row;
    float z = accb[reg];
    float sv = z / (1.0f + __expf(-z));
    out[(size_t)m * 128 + nq] = sv + accs[reg];
  }
}

extern "C" void kernel_launch(void* const* d_in, const int* in_sizes, int n_in,
                              void* d_out, int out_size, void* d_ws, size_t ws_size,
                              hipStream_t stream) {
  const float* x  = (const float*)d_in[0];   // [16384][1024] f32
  const float* wb = (const float*)d_in[1];   // [1024][128]   f32
  const float* ws = (const float*)d_in[2];   // [1024][128][8] f32
  u16* wst = (u16*)d_ws;                     // [6][128][1024] bf16 = 1.5 MB
  float* out = (float*)d_out;                // [16384][128]  f32

  kan_prep<<<dim3(32, 4), 256, 0, stream>>>(wb, ws, wst);
  kan_main<<<dim3(512), 256, 0, stream>>>(x, wst, out);
}

// Round 5
// 170.446 us; speedup vs baseline: 1.0159x; 1.0159x over previous
//
#include <hip/hip_runtime.h>

typedef unsigned short u16;
typedef unsigned int u32;
typedef __bf16 bf16x8 __attribute__((ext_vector_type(8)));
typedef float f32x16 __attribute__((ext_vector_type(16)));

#define C2 (-7.213475204444817f) /* -5/ln2 : exp(-5 t^2) = exp2(C2 t^2) */
#define T1C 0.28650480f          /* e^-1.25 */
#define T2C 0.0067379470f        /* e^-5    */

__device__ __forceinline__ u16 f2bf(float f) {
  u32 u = __float_as_uint(f);
  return (u16)((u + 0x7FFFu + ((u >> 16) & 1u)) >> 16);  // RNE
}

__device__ __forceinline__ void async16(const void* g, void* l) {
  __builtin_amdgcn_global_load_lds(
      (const __attribute__((address_space(1))) u32*)g,
      (__attribute__((address_space(3))) u32*)l, 16, 0, 0);
}

__device__ __forceinline__ f32x16 mfma16(uint4 a, uint4 b, f32x16 c) {
  return __builtin_amdgcn_mfma_f32_32x32x16_bf16(
      __builtin_bit_cast(bf16x8, a), __builtin_bit_cast(bf16x8, b), c, 0, 0, 0);
}

// ---------------------------------------------------------------------------
// Prep (unchanged; validated R3/R4): f32 weights -> bf16 transposed.
// wst[s][u][d]: s=0..4 -> spline_weight[d][u][s]; s=5 -> base_weight[d][u].
// ---------------------------------------------------------------------------
__global__ __launch_bounds__(256) void kan_prep(const float* __restrict__ wb,
                                                const float* __restrict__ ws,
                                                u16* __restrict__ wst) {
  __shared__ __align__(16) u16 tile[6][32][40];
  const int t = threadIdx.x;
  const int d0 = blockIdx.x * 32;
  const int u0 = blockIdx.y * 32;
#pragma unroll
  for (int it = 0; it < 4; ++it) {
    int e = it * 256 + t;
    int uu = e & 31, dd = e >> 5;
    const float* p = ws + ((size_t)(d0 + dd) * 128 + (u0 + uu)) * 8;
    float4 v0 = *(const float4*)p;
    float g4 = p[4];
    tile[0][uu][dd] = f2bf(v0.x);
    tile[1][uu][dd] = f2bf(v0.y);
    tile[2][uu][dd] = f2bf(v0.z);
    tile[3][uu][dd] = f2bf(v0.w);
    tile[4][uu][dd] = f2bf(g4);
    tile[5][uu][dd] = f2bf(wb[(size_t)(d0 + dd) * 128 + (u0 + uu)]);
  }
  __syncthreads();
#pragma unroll
  for (int it = 0; it < 3; ++it) {
    int v = it * 256 + t;
    int s = v >> 7;
    int r = v & 127;
    int uu = r >> 2, dseg = r & 3;
    uint4 val = *(const uint4*)&tile[s][uu][dseg * 8];
    *(uint4*)(wst + (size_t)(s * 128 + u0 + uu) * 1024 + d0 + dseg * 8) = val;
  }
}

// ---------------------------------------------------------------------------
// Main. grid 256, block 512 thr = 8 waves (wm, wn, kks), tile M=64 N=128.
// Wave tile 32m x 64n; kk-split: wave kks handles k-half kks of each BK=32
// chunk (partial sums merged in LDS epilogue).
// As: rbf subs 0..4 + bf16(x) sub 5, computed ONCE per block (k-strip
// writers, coalesced x loads), stored frag-order:
//   byte = s*4096 + (g*2+kk)*1024 + lane*16   (g = m-half)
// Bs: DMA'd frag-order: byte = 24576 + s*8192 + (kk*4 + nn)*1024 + lane*16
// Frag-order => every ds access is lane-linear 16B granules: conflict-free.
// Double-buffered 2 x 72 KB = 144 KB, one barrier per chunk.
// mfma A[m=lane&31][k=(lane>>5)*8+j]; C/D col=lane&31,
// row=(reg&3)+8*(reg>>2)+4*(lane>>5)   (validated R2-R4).
// ---------------------------------------------------------------------------
__global__ __launch_bounds__(512, 1) void kan_main(const float* __restrict__ x,
                                                   const u16* __restrict__ wst,
                                                   float* __restrict__ out) {
  __shared__ __align__(16) char lds[147456];  // 2 x 73728

  const int t = threadIdx.x;
  const int lane = t & 63;
  const int w = t >> 6;           // 0..7
  const int wm = (w >> 2) & 1, wn = (w >> 1) & 1, kks = w & 1;
  const int b0 = blockIdx.x * 64;
  const int kh = lane >> 5;

  f32x16 accs[2], accb[2];
#pragma unroll
  for (int i = 0; i < 16; ++i) {
    accs[0][i] = 0.f; accs[1][i] = 0.f;
    accb[0][i] = 0.f; accb[1][i] = 0.f;
  }

  // ---- rbf writer mapping: thread t owns row r=t>>3, k-cols (t&7)*4..+4
  //      -> frag (g=r>>5, kk=(t>>2)&1), lane wl, byte-half t&1
  const int wr_l = ((t >> 1) & 1) * 32 + ((t >> 3) & 31);
  const u32 aw = (u32)(((((t >> 8) & 1) * 2 + ((t >> 2) & 1)) << 10) +
                       wr_l * 16 + (t & 1) * 8);
  const float* xp = x + (size_t)(b0 + (t >> 3)) * 1024 + (t & 7) * 4;

  // ---- DMA mapping: sub s -> dst granule s*512+t; decode src (kk,nn,l)
  const u16* dsrc = wst + (size_t)(((t >> 6) & 3) * 32 + (t & 31)) * 1024 +
                    (((t >> 8) & 1) << 4) + (((t >> 5) & 1) << 3);

  // ---- reader offsets
  const u32 ao = (u32)((wm * 2 + kks) * 1024 + lane * 16);           // + s*4096
  const u32 bo = (u32)(24576 + (kks * 4 + wn * 2) * 1024 + lane * 16);  // + s*8192 (+1024 for nt=1)

  auto dma = [&](int k0, char* buf) {
    const u16* s0 = dsrc + k0;
    char* d0 = buf + 24576 + t * 16;
#pragma unroll
    for (int s = 0; s < 6; ++s) async16(s0 + (size_t)s * 131072, d0 + s * 8192);
  };

  auto rbf_write = [&](char* buf, float4 xa) {
    float xf[4] = {xa.x, xa.y, xa.z, xa.w};
    u32 rb[6][4];
#pragma unroll
    for (int e = 0; e < 4; ++e) {
      float xv = xf[e];
      float t0 = C2 * xv;
      float P = __builtin_amdgcn_exp2f(t0 * xv);  // e^{-5x^2}
      float Qp = __builtin_amdgcn_exp2f(-t0);     // e^{+5x}
      float Qm = __builtin_amdgcn_exp2f(t0);      // e^{-5x}
      float PQ = P * Qp, PQm = P * Qm;
      rb[0][e] = __float_as_uint(PQm * Qm * T2C) + 0x8000u;
      rb[1][e] = __float_as_uint(PQm * T1C) + 0x8000u;
      rb[2][e] = __float_as_uint(P) + 0x8000u;
      rb[3][e] = __float_as_uint(PQ * T1C) + 0x8000u;
      rb[4][e] = __float_as_uint(PQ * Qp * T2C) + 0x8000u;
      rb[5][e] = __float_as_uint(xv) + 0x8000u;
    }
#pragma unroll
    for (int s = 0; s < 6; ++s) {
      uint2 pk;
      pk.x = __builtin_amdgcn_perm(rb[s][1], rb[s][0], 0x07060302);
      pk.y = __builtin_amdgcn_perm(rb[s][3], rb[s][2], 0x07060302);
      *(uint2*)(buf + s * 4096 + aw) = pk;
    }
  };

  // ---- pipeline
  float4 xreg = *(const float4*)(xp);
  dma(0, lds);
  rbf_write(lds, xreg);
  xreg = *(const float4*)(xp + 32);
  __syncthreads();

  for (int k = 0; k < 32; ++k) {
    char* cur = lds + (size_t)(k & 1) * 73728;
    if (k < 31) {
      char* nxt = lds + (size_t)((k + 1) & 1) * 73728;
      dma((k + 1) * 32, nxt);       // async, drained at this chunk's barrier
      rbf_write(nxt, xreg);
      if (k < 30) xreg = *(const float4*)(xp + (k + 2) * 32);
    }
#pragma unroll
    for (int s = 0; s < 6; ++s) {
      uint4 a  = *(const uint4*)(cur + s * 4096 + ao);
      uint4 v0 = *(const uint4*)(cur + s * 8192 + bo);
      uint4 v1 = *(const uint4*)(cur + s * 8192 + bo + 1024);
      if (s < 5) {
        accs[0] = mfma16(a, v0, accs[0]);
        accs[1] = mfma16(a, v1, accs[1]);
      } else {
        accb[0] = mfma16(a, v0, accb[0]);
        accb[1] = mfma16(a, v1, accb[1]);
      }
    }
    __syncthreads();
  }

  // ---- epilogue: merge kks partials via LDS (4 rounds of 4 regs), then
  //      silu(base)+spline, f32 stores. Frag-order slabs: conflict-free.
  const int pw = w ^ 1;  // partner wave (other kks)
#pragma unroll
  for (int q = 0; q < 4; ++q) {
    // write own 4 vectors' regs [4q..4q+4) : slab byte = (w*4+v)*1024 + lane*16
    {
      float4 s0 = make_float4(accs[0][4 * q], accs[0][4 * q + 1], accs[0][4 * q + 2], accs[0][4 * q + 3]);
      float4 s1 = make_float4(accs[1][4 * q], accs[1][4 * q + 1], accs[1][4 * q + 2], accs[1][4 * q + 3]);
      float4 b0v = make_float4(accb[0][4 * q], accb[0][4 * q + 1], accb[0][4 * q + 2], accb[0][4 * q + 3]);
      float4 b1v = make_float4(accb[1][4 * q], accb[1][4 * q + 1], accb[1][4 * q + 2], accb[1][4 * q + 3]);
      *(float4*)(lds + (w * 4 + 0) * 1024 + lane * 16) = s0;
      *(float4*)(lds + (w * 4 + 1) * 1024 + lane * 16) = s1;
      *(float4*)(lds + (w * 4 + 2) * 1024 + lane * 16) = b0v;
      *(float4*)(lds + (w * 4 + 3) * 1024 + lane * 16) = b1v;
    }
    __syncthreads();
    if (kks == 0) {
      float4 ps0 = *(const float4*)(lds + (pw * 4 + 0) * 1024 + lane * 16);
      float4 ps1 = *(const float4*)(lds + (pw * 4 + 1) * 1024 + lane * 16);
      float4 pb0 = *(const float4*)(lds + (pw * 4 + 2) * 1024 + lane * 16);
      float4 pb1 = *(const float4*)(lds + (pw * 4 + 3) * 1024 + lane * 16);
      const float* ps0f = &ps0.x; const float* ps1f = &ps1.x;
      const float* pb0f = &pb0.x; const float* pb1f = &pb1.x;
#pragma unroll
      for (int rr = 0; rr < 4; ++rr) {
        int reg = 4 * q + rr;
        int row = rr + 8 * q + 4 * kh;
        size_t m = (size_t)(b0 + wm * 32 + row);
        int n0 = wn * 64 + (lane & 31);
        float z0 = accb[0][reg] + pb0f[rr];
        float z1 = accb[1][reg] + pb1f[rr];
        float o0 = z0 / (1.0f + __expf(-z0)) + accs[0][reg] + ps0f[rr];
        float o1 = z1 / (1.0f + __expf(-z1)) + accs[1][reg] + ps1f[rr];
        out[m * 128 + n0] = o0;
        out[m * 128 + n0 + 32] = o1;
      }
    }
    __syncthreads();
  }
}

extern "C" void kernel_launch(void* const* d_in, const int* in_sizes, int n_in,
                              void* d_out, int out_size, void* d_ws, size_t ws_size,
                              hipStream_t stream) {
  const float* x  = (const float*)d_in[0];   // [16384][1024] f32
  const float* wb = (const float*)d_in[1];   // [1024][128]   f32
  const float* ws = (const float*)d_in[2];   // [1024][128][8] f32
  u16* wst = (u16*)d_ws;                     // [6][128][1024] bf16 = 1.5 MB
  float* out = (float*)d_out;                // [16384][128]  f32

  kan_prep<<<dim3(32, 4), 256, 0, stream>>>(wb, ws, wst);
  kan_main<<<dim3(256), 512, 0, stream>>>(x, wst, out);
}

// Round 6
// 151.806 us; speedup vs baseline: 1.1407x; 1.1228x over previous
//
#include <hip/hip_runtime.h>

typedef unsigned short u16;
typedef unsigned int u32;
typedef __bf16 bf16x8 __attribute__((ext_vector_type(8)));
typedef float f32x16 __attribute__((ext_vector_type(16)));

#define C2 (-7.213475204444817f) /* -5/ln2 : exp(-5 t^2) = exp2(C2 t^2) */
#define T1C 0.28650480f          /* e^-1.25 */
#define T2C 0.0067379470f        /* e^-5    */

__device__ __forceinline__ u16 f2bf(float f) {
  u32 u = __float_as_uint(f);
  return (u16)((u + 0x7FFFu + ((u >> 16) & 1u)) >> 16);  // RNE
}

__device__ __forceinline__ void async16(const void* g, void* l) {
  __builtin_amdgcn_global_load_lds(
      (const __attribute__((address_space(1))) u32*)g,
      (__attribute__((address_space(3))) u32*)l, 16, 0, 0);
}

__device__ __forceinline__ f32x16 mfma16(uint4 a, uint4 b, f32x16 c) {
  return __builtin_amdgcn_mfma_f32_32x32x16_bf16(
      __builtin_bit_cast(bf16x8, a), __builtin_bit_cast(bf16x8, b), c, 0, 0, 0);
}

// ---------------------------------------------------------------------------
// Prep: f32 weights -> bf16 in PER-CHUNK FRAGMENT ORDER, so the main kernel's
// global_load_lds reads are contiguous (kills the 64-line/inst TA gather).
// wst2 layout, 16-B granules: granule(c, s*512 + t) where
//   u(t) = ((t>>6)&3)*32 + (t&31),  k(t) = c*32 + ((t>>8)&1)*16 + ((t>>5)&1)*8
//   content = W_s[k(t)..k(t)+8)[u(t)]   (s=0..4 spline g, s=5 base)
// Block (c, ub): LDS-tiled transpose of a 32d x 32u slab; in+out coalesced.
// ---------------------------------------------------------------------------
__global__ __launch_bounds__(256) void kan_prep(const float* __restrict__ wb,
                                                const float* __restrict__ ws,
                                                u16* __restrict__ wst2) {
  __shared__ u16 tile[6][32][34];  // d x u, pad 34 (non-pow2)
  const int tid = threadIdx.x;
  const int c = blockIdx.x, ub = blockIdx.y;
#pragma unroll
  for (int it = 0; it < 4; ++it) {
    int e = it * 256 + tid;
    int dd = e >> 5, uu = e & 31;
    size_t base = (size_t)(c * 32 + dd) * 128 + ub * 32 + uu;
    const float* p = ws + base * 8;
    float4 v0 = *(const float4*)p;  // g = 0..3
    float g4 = p[4];
    tile[0][dd][uu] = f2bf(v0.x);
    tile[1][dd][uu] = f2bf(v0.y);
    tile[2][dd][uu] = f2bf(v0.z);
    tile[3][dd][uu] = f2bf(v0.w);
    tile[4][dd][uu] = f2bf(g4);
    tile[5][dd][uu] = f2bf(wb[base]);
  }
  __syncthreads();
#pragma unroll
  for (int it = 0; it < 3; ++it) {
    int idx = it * 256 + tid;          // 768 granules per block
    int s = idx >> 7, r = idx & 127;
    int b8 = r >> 6, b5 = (r >> 5) & 1, l = r & 31;
    int dbase = b8 * 16 + b5 * 8;
    u32 q[4];
#pragma unroll
    for (int j = 0; j < 4; ++j) {
      u32 lo = tile[s][dbase + 2 * j][l];
      u32 hi = tile[s][dbase + 2 * j + 1][l];
      q[j] = lo | (hi << 16);
    }
    uint4 w4; w4.x = q[0]; w4.y = q[1]; w4.z = q[2]; w4.w = q[3];
    *(uint4*)(wst2 + (size_t)c * 24576 +
              (size_t)(s * 512 + b8 * 256 + ub * 64 + b5 * 32 + l) * 8) = w4;
  }
}

// ---------------------------------------------------------------------------
// Main. grid 256, block 512 = 8 waves (wm, wn, kks), tile M=64 N=128, BK=32.
// kk-split: wave kks handles k-half kks (partials merged in LDS epilogue).
// As: rbf subs 0..4 + bf16(x) sub 5: byte = s*4096 + (g*2+kk)*1024 + lane*16.
//   Writers: wave (g,kk,h)=w bits, lane ll writes 8 B at +h*512+ll*8 — one
//   contiguous 512-B run per wave => 2-way banks = free.  Thread's x-values:
//   row g*32+(ll>>1), k = kk*16 + h*8 + (ll&1)*4 + 0..3.
// Bs: DMA frag-order from wst2: src byte = k*49152 + s*8192 + t*16 (wave reads
//   1024 contiguous B), dst = 24576 + s*8192 + t*16.
// Reads all lane-linear 16-B granules: conflict-free.  Dbuf 2x72 KB.
// mfma A[m=lane&31][k=(lane>>5)*8+j]; C/D col=lane&31,
// row=(reg&3)+8*(reg>>2)+4*(lane>>5)   (validated R2-R5).
// ---------------------------------------------------------------------------
__global__ __launch_bounds__(512, 1) void kan_main(const float* __restrict__ x,
                                                   const u16* __restrict__ wst2,
                                                   float* __restrict__ out) {
  __shared__ __align__(16) char lds[147456];  // 2 x 73728

  const int t = threadIdx.x;
  const int lane = t & 63;
  const int w = t >> 6;           // 0..7
  const int wm = (w >> 2) & 1, wn = (w >> 1) & 1, kks = w & 1;
  const int b0 = blockIdx.x * 64;
  const int kh = lane >> 5;

  f32x16 accs[2], accb[2];
#pragma unroll
  for (int i = 0; i < 16; ++i) {
    accs[0][i] = 0.f; accs[1][i] = 0.f;
    accb[0][i] = 0.f; accb[1][i] = 0.f;
  }

  // ---- rbf writer mapping (conflict-free): wave bits g,kk,h; lane ll
  const int wg = (w >> 2) & 1, wkk = (w >> 1) & 1, wh = w & 1;
  const u32 aw = (u32)((wg * 2 + wkk) * 1024 + wh * 512 + lane * 8);  // + s*4096
  const float* xp = x + (size_t)(b0 + wg * 32 + (lane >> 1)) * 1024 +
                    wkk * 16 + wh * 8 + (lane & 1) * 4;

  // ---- DMA: contiguous src from wst2; dst granule = s*512 + t
  const char* dsrcb = (const char*)wst2 + t * 16;

  // ---- reader offsets
  const u32 ao = (u32)((wm * 2 + kks) * 1024 + lane * 16);               // + s*4096
  const u32 bo = (u32)(24576 + (kks * 4 + wn * 2) * 1024 + lane * 16);   // + s*8192 (+1024 nt=1)

  auto dma = [&](int k1, char* buf) {
    const char* s0 = dsrcb + (size_t)k1 * 49152;
    char* d0 = buf + 24576 + t * 16;
#pragma unroll
    for (int s = 0; s < 6; ++s) async16(s0 + s * 8192, d0 + s * 8192);
  };

  auto rbf_write = [&](char* buf, float4 xa) {
    float xf[4] = {xa.x, xa.y, xa.z, xa.w};
    u32 rb[6][4];
#pragma unroll
    for (int e = 0; e < 4; ++e) {
      float xv = xf[e];
      float t0 = C2 * xv;
      float P = __builtin_amdgcn_exp2f(t0 * xv);  // e^{-5x^2}
      float Qp = __builtin_amdgcn_exp2f(-t0);     // e^{+5x}
      float Qm = __builtin_amdgcn_exp2f(t0);      // e^{-5x}
      float PQ = P * Qp, PQm = P * Qm;
      rb[0][e] = __float_as_uint(PQm * Qm * T2C) + 0x8000u;
      rb[1][e] = __float_as_uint(PQm * T1C) + 0x8000u;
      rb[2][e] = __float_as_uint(P) + 0x8000u;
      rb[3][e] = __float_as_uint(PQ * T1C) + 0x8000u;
      rb[4][e] = __float_as_uint(PQ * Qp * T2C) + 0x8000u;
      rb[5][e] = __float_as_uint(xv) + 0x8000u;
    }
#pragma unroll
    for (int s = 0; s < 6; ++s) {
      uint2 pk;
      pk.x = __builtin_amdgcn_perm(rb[s][1], rb[s][0], 0x07060302);
      pk.y = __builtin_amdgcn_perm(rb[s][3], rb[s][2], 0x07060302);
      *(uint2*)(buf + s * 4096 + aw) = pk;
    }
  };

  // ---- pipeline
  float4 xreg = *(const float4*)(xp);
  dma(0, lds);
  rbf_write(lds, xreg);
  xreg = *(const float4*)(xp + 32);
  __syncthreads();

  for (int k = 0; k < 32; ++k) {
    char* cur = lds + (size_t)(k & 1) * 73728;
    if (k < 31) {
      char* nxt = lds + (size_t)((k + 1) & 1) * 73728;
      dma(k + 1, nxt);              // async, drained at this chunk's barrier
      rbf_write(nxt, xreg);
      if (k < 30) xreg = *(const float4*)(xp + (k + 2) * 32);
    }
#pragma unroll
    for (int s = 0; s < 6; ++s) {
      uint4 a  = *(const uint4*)(cur + s * 4096 + ao);
      uint4 v0 = *(const uint4*)(cur + s * 8192 + bo);
      uint4 v1 = *(const uint4*)(cur + s * 8192 + bo + 1024);
      if (s < 5) {
        accs[0] = mfma16(a, v0, accs[0]);
        accs[1] = mfma16(a, v1, accs[1]);
      } else {
        accb[0] = mfma16(a, v0, accb[0]);
        accb[1] = mfma16(a, v1, accb[1]);
      }
    }
    __syncthreads();
  }

  // ---- epilogue: merge kks partials via LDS, silu(base)+spline, f32 stores
  const int pw = w ^ 1;  // partner wave (other kks)
#pragma unroll
  for (int q = 0; q < 4; ++q) {
    {
      float4 s0 = make_float4(accs[0][4 * q], accs[0][4 * q + 1], accs[0][4 * q + 2], accs[0][4 * q + 3]);
      float4 s1 = make_float4(accs[1][4 * q], accs[1][4 * q + 1], accs[1][4 * q + 2], accs[1][4 * q + 3]);
      float4 b0v = make_float4(accb[0][4 * q], accb[0][4 * q + 1], accb[0][4 * q + 2], accb[0][4 * q + 3]);
      float4 b1v = make_float4(accb[1][4 * q], accb[1][4 * q + 1], accb[1][4 * q + 2], accb[1][4 * q + 3]);
      *(float4*)(lds + (w * 4 + 0) * 1024 + lane * 16) = s0;
      *(float4*)(lds + (w * 4 + 1) * 1024 + lane * 16) = s1;
      *(float4*)(lds + (w * 4 + 2) * 1024 + lane * 16) = b0v;
      *(float4*)(lds + (w * 4 + 3) * 1024 + lane * 16) = b1v;
    }
    __syncthreads();
    if (kks == 0) {
      float4 ps0 = *(const float4*)(lds + (pw * 4 + 0) * 1024 + lane * 16);
      float4 ps1 = *(const float4*)(lds + (pw * 4 + 1) * 1024 + lane * 16);
      float4 pb0 = *(const float4*)(lds + (pw * 4 + 2) * 1024 + lane * 16);
      float4 pb1 = *(const float4*)(lds + (pw * 4 + 3) * 1024 + lane * 16);
      const float* ps0f = &ps0.x; const float* ps1f = &ps1.x;
      const float* pb0f = &pb0.x; const float* pb1f = &pb1.x;
#pragma unroll
      for (int rr = 0; rr < 4; ++rr) {
        int reg = 4 * q + rr;
        int row = rr + 8 * q + 4 * kh;
        size_t m = (size_t)(b0 + wm * 32 + row);
        int n0 = wn * 64 + (lane & 31);
        float z0 = accb[0][reg] + pb0f[rr];
        float z1 = accb[1][reg] + pb1f[rr];
        float o0 = z0 / (1.0f + __expf(-z0)) + accs[0][reg] + ps0f[rr];
        float o1 = z1 / (1.0f + __expf(-z1)) + accs[1][reg] + ps1f[rr];
        out[m * 128 + n0] = o0;
        out[m * 128 + n0 + 32] = o1;
      }
    }
    __syncthreads();
  }
}

extern "C" void kernel_launch(void* const* d_in, const int* in_sizes, int n_in,
                              void* d_out, int out_size, void* d_ws, size_t ws_size,
                              hipStream_t stream) {
  const float* x  = (const float*)d_in[0];   // [16384][1024] f32
  const float* wb = (const float*)d_in[1];   // [1024][128]   f32
  const float* ws = (const float*)d_in[2];   // [1024][128][8] f32
  u16* wst2 = (u16*)d_ws;                    // [32][3072] granules, 1.5 MB
  float* out = (float*)d_out;                // [16384][128]  f32

  kan_prep<<<dim3(32, 4), 256, 0, stream>>>(wb, ws, wst2);
  kan_main<<<dim3(256), 512, 0, stream>>>(x, wst2, out);
}